// Round 2
// baseline (558.150 us; speedup 1.0000x reference)
//
#include <hip/hip_runtime.h>

typedef unsigned int uint_t;

constexpr int B = 8;
constexpr int N = 1024;
constexpr int NBLOCKS = 256;
constexpr int NTHREADS = 512;
constexpr int NWAVES = NTHREADS / 64;      // 8
constexpr int BPB = NBLOCKS / B;           // 32 blocks per batch
constexpr int SEG = N / BPB;               // 32 rows per block
constexpr int RPW = SEG / NWAVES;          // 4 rows per wave
constexpr int KPL = N / 64;                // 16 columns per lane
constexpr int MAX_ITER = 100;
constexpr float THRESH = 0.1f;
constexpr float K2 = 14.42695040888963f;        // log2(e)/EPS
constexpr float A2K = 2.0f * K2;
constexpr float NEPSLN2 = -0.06931471805599453f; // -EPS*ln2
constexpr float EPSLOGMU = -0.693146156565634f;  // EPS*log(1/N+1e-8)
constexpr uint_t MAGIC = 0xC0FFEE01u;

// ws word offsets
constexpr int OFF_U      = 0;                    // [B][N]
constexpr int OFF_V      = OFF_U + B * N;        // [B][N]
constexpr int OFF_ERRBLK = OFF_V + B * N;        // [B][32]
constexpr int OFF_ERRBAT = OFF_ERRBLK + 256;     // [100][8]
constexpr int OFF_ERRPUB = OFF_ERRBAT + 800;     // [100] uint
constexpr int OFF_EMDBLK = OFF_ERRPUB + 100;     // [B][32]
constexpr int OFF_EMDBAT = OFF_EMDBLK + 256;     // [8]
constexpr int OFF_EMDPUB = OFF_EMDBAT + 8;       // [1]
constexpr int OFF_INIT   = OFF_EMDPUB + 1;       // [1]
constexpr int OFF_BARCNT = 17824;                // [8] stride 32 (128B apart)
constexpr int OFF_END    = OFF_BARCNT + 8 * 32;  // 18080 words (~72 KB)

__device__ __forceinline__ float wsum(float v) {
#pragma unroll
  for (int o = 32; o; o >>= 1) v += __shfl_xor(v, o);
  return v;
}
__device__ __forceinline__ float wmax(float v) {
#pragma unroll
  for (int o = 32; o; o >>= 1) v = fmaxf(v, __shfl_xor(v, o));
  return v;
}

// Deterministic block-wide sum; every thread returns the same value.
__device__ __forceinline__ float block_sum(float v, float* sh) {
  v = wsum(v);
  const int wave = threadIdx.x >> 6;
  const int lane = threadIdx.x & 63;
  if (lane == 0) sh[wave] = v;
  __syncthreads();
  float tot = 0.f;
#pragma unroll
  for (int w = 0; w < NWAVES; ++w) tot += sh[w];
  __syncthreads();
  return tot;
}

// Per-batch barrier over 32 blocks: monotone counter, agent-scope atomics.
// __threadfence before arrive makes this block's global stores visible
// (cross-XCD); __threadfence after release kills stale cached lines.
__device__ __forceinline__ void batch_barrier(uint_t* cnt, uint_t target) {
  __threadfence();
  __syncthreads();
  if (threadIdx.x == 0) {
    __hip_atomic_fetch_add(cnt, 1u, __ATOMIC_ACQ_REL, __HIP_MEMORY_SCOPE_AGENT);
    while (__hip_atomic_load(cnt, __ATOMIC_ACQUIRE, __HIP_MEMORY_SCOPE_AGENT) < target)
      __builtin_amdgcn_s_sleep(2);
  }
  __syncthreads();
  __threadfence();
}

// One Sinkhorn half-update: pout[i] = EPS*(log_mu - lse_cols((pin_j - C_ij)/EPS))
// All math in base-2 scale (K2 = log2(e)/EPS folded into staged data).
template <bool TRACK>
__device__ __forceinline__ float half_update(
    const float4* s_row, const float4* s_col,
    const float* __restrict__ pin, float* __restrict__ pout,
    int seg, int wave, int lane, bool pin_zero, bool first_out) {
  float p2[KPL];
#pragma unroll
  for (int k = 0; k < KPL; ++k)
    p2[k] = pin_zero ? 0.f : pin[lane + (k << 6)] * K2;

  float err = 0.f;
  float a0[RPW], a1[RPW], a2[RPW], X[RPW], m[RPW];
  float vals[RPW][KPL];
#pragma unroll
  for (int rr = 0; rr < RPW; ++rr) {
    float4 r4 = s_row[seg * SEG + wave * RPW + rr];  // wave-uniform: broadcast
    a0[rr] = A2K * r4.x; a1[rr] = A2K * r4.y; a2[rr] = A2K * r4.z;
    X[rr] = -r4.w;        // = K2*|row|^2
    m[rr] = -3.4e38f;
  }
#pragma unroll
  for (int k = 0; k < KPL; ++k) {
    float4 c4 = s_col[lane + (k << 6)];  // ds_read_b128, dense
    float pv = p2[k];
#pragma unroll
    for (int rr = 0; rr < RPW; ++rr) {
      // t = 2*K2*dot - K2*|col|^2 ; K2*C = max(X - t, 0)
      float t = fmaf(a0[rr], c4.x, fmaf(a1[rr], c4.y, fmaf(a2[rr], c4.z, c4.w)));
      float val = fminf(t - X[rr], 0.f) + pv;   // = pv - K2*C
      vals[rr][k] = val;
      m[rr] = fmaxf(m[rr], val);
    }
  }
#pragma unroll
  for (int rr = 0; rr < RPW; ++rr) {
    float mr = wmax(m[rr]);
    float s = 0.f;
#pragma unroll
    for (int k = 0; k < KPL; ++k)
      s += __builtin_amdgcn_exp2f(vals[rr][k] - mr);
    s = wsum(s);
    float lse2 = mr + __builtin_amdgcn_logf(s);       // log2(sum 2^val)
    float pnew = fmaf(NEPSLN2, lse2, EPSLOGMU);
    if (lane == 0) {
      int i = seg * SEG + wave * RPW + rr;
      if (TRACK) {
        float old = first_out ? 0.f : pout[i];
        err += fabsf(pnew - old);
      }
      pout[i] = pnew;
    }
  }
  return err;
}

__global__ void __launch_bounds__(NTHREADS, 1) sinkhorn_kernel(
    const float* __restrict__ xg, const float* __restrict__ yg,
    float* __restrict__ out, float* __restrict__ ws) {
  __shared__ float4 s_x4[N];   // (x0,x1,x2, -K2*|x|^2)
  __shared__ float4 s_y4[N];
  __shared__ float sh_red[NWAVES];

  const int bid = blockIdx.x;
  const int tid = threadIdx.x;
  const int b = bid & 7;       // batch; with bid%8->XCD round-robin this is XCD-local
  const int seg = bid >> 3;
  const int wave = tid >> 6;
  const int lane = tid & 63;

  float* u = ws + OFF_U + b * N;
  float* v = ws + OFF_V + b * N;
  float* err_blk = ws + OFF_ERRBLK + b * 32;
  float* err_bat = ws + OFF_ERRBAT;
  uint_t* err_pub = (uint_t*)(ws + OFF_ERRPUB);
  float* emd_blk = ws + OFF_EMDBLK + b * 32;
  float* emd_bat = ws + OFF_EMDBAT;
  uint_t* emd_pub = (uint_t*)(ws + OFF_EMDPUB);
  uint_t* init_flag = (uint_t*)(ws + OFF_INIT);
  uint_t* bar_cnt = (uint_t*)(ws + OFF_BARCNT) + b * 32;

  // Stage points into LDS (overlaps with init handshake below).
  for (int p = tid; p < N; p += NTHREADS) {
    const float* xp = xg + (size_t)(b * N + p) * 3;
    float x0 = xp[0], x1 = xp[1], x2 = xp[2];
    s_x4[p] = make_float4(x0, x1, x2, -K2 * (x0 * x0 + x1 * x1 + x2 * x2));
    const float* yp = yg + (size_t)(b * N + p) * 3;
    float y0 = yp[0], y1 = yp[1], y2 = yp[2];
    s_y4[p] = make_float4(y0, y1, y2, -K2 * (y0 * y0 + y1 * y1 + y2 * y2));
  }

  // Init handshake: block 0 zeroes all counters (ws is poisoned 0xAA),
  // then broadcasts MAGIC. Poison != MAGIC, so spin is safe. u/v need no
  // init: iteration 0 uses pin_zero/first_out (u=v=0 algebraically).
  if (bid == 0) {
    for (int i = tid; i < OFF_END - OFF_ERRPUB; i += NTHREADS)
      ((uint_t*)(ws + OFF_ERRPUB))[i] = 0u;
    __threadfence();
    __syncthreads();
    if (tid == 0)
      __hip_atomic_store(init_flag, MAGIC, __ATOMIC_RELEASE, __HIP_MEMORY_SCOPE_AGENT);
  } else {
    if (tid == 0)
      while (__hip_atomic_load(init_flag, __ATOMIC_ACQUIRE, __HIP_MEMORY_SCOPE_AGENT) != MAGIC)
        __builtin_amdgcn_s_sleep(2);
  }
  __syncthreads();
  __threadfence();

  uint_t bar_target = 0;
  for (int it = 0; it < MAX_ITER; ++it) {
    // ---- u-update (+ err tracking on own rows) ----
    float my_err = half_update<true>(s_x4, s_y4, v, u, seg, wave, lane,
                                     /*pin_zero=*/it == 0, /*first_out=*/it == 0);
    float blk_err = block_sum(my_err, sh_red);
    if (tid == 0) err_blk[seg] = blk_err;
    bar_target += BPB;
    batch_barrier(bar_cnt, bar_target);   // u + err_blk visible within batch

    // Publish this batch's err early: propagation overlaps v-update compute.
    if (seg == 0 && tid == 0) {
      float s = 0.f;
      for (int q = 0; q < BPB; ++q) s += err_blk[q];
      err_bat[it * B + b] = s;
      __threadfence();
      __hip_atomic_fetch_add(&err_pub[it], 1u, __ATOMIC_RELEASE, __HIP_MEMORY_SCOPE_AGENT);
    }

    // ---- v-update (uses new u) ----
    half_update<false>(s_y4, s_x4, u, v, seg, wave, lane, false, false);
    bar_target += BPB;
    batch_barrier(bar_cnt, bar_target);   // v visible within batch

    // ---- global convergence decision (uniform across all blocks) ----
    if (tid == 0)
      while (__hip_atomic_load(&err_pub[it], __ATOMIC_ACQUIRE, __HIP_MEMORY_SCOPE_AGENT) < (uint_t)B)
        __builtin_amdgcn_s_sleep(2);
    __syncthreads();
    __threadfence();
    float tot = 0.f;
#pragma unroll
    for (int q = 0; q < B; ++q) tot += err_bat[it * B + q];
    if (tot * (1.f / (B * N)) < THRESH) break;
  }

  // ---- epilogue: emd_b = sum_ij exp((u_i+v_j-C)/EPS)*C  (x K2 scale) ----
  float p2[KPL];
#pragma unroll
  for (int k = 0; k < KPL; ++k) p2[k] = v[lane + (k << 6)] * K2;
  float acc = 0.f;
#pragma unroll
  for (int rr = 0; rr < RPW; ++rr) {
    int i = seg * SEG + wave * RPW + rr;
    float4 r4 = s_x4[i];
    float a0 = A2K * r4.x, a1 = A2K * r4.y, a2 = A2K * r4.z;
    float X = -r4.w;
    float u2 = u[i] * K2;
#pragma unroll
    for (int k = 0; k < KPL; ++k) {
      float4 c4 = s_y4[lane + (k << 6)];
      float t = fmaf(a0, c4.x, fmaf(a1, c4.y, fmaf(a2, c4.z, c4.w)));
      float kc = fmaxf(X - t, 0.f);   // K2*C
      acc = fmaf(__builtin_amdgcn_exp2f(u2 + p2[k] - kc), kc, acc);
    }
  }
  float blk = block_sum(acc, sh_red);
  if (tid == 0) emd_blk[seg] = blk;
  bar_target += BPB;
  batch_barrier(bar_cnt, bar_target);
  if (seg == 0 && tid == 0) {
    float s = 0.f;
    for (int q = 0; q < BPB; ++q) s += emd_blk[q];
    emd_bat[b] = s;
    __threadfence();
    __hip_atomic_fetch_add(emd_pub, 1u, __ATOMIC_RELEASE, __HIP_MEMORY_SCOPE_AGENT);
  }
  if (bid == 0 && tid == 0) {
    while (__hip_atomic_load(emd_pub, __ATOMIC_ACQUIRE, __HIP_MEMORY_SCOPE_AGENT) < (uint_t)B)
      __builtin_amdgcn_s_sleep(2);
    __threadfence();
    float s = 0.f;
#pragma unroll
    for (int q = 0; q < B; ++q) s += emd_bat[q];
    out[0] = s * (1.f / (B * K2));
  }
}

extern "C" void kernel_launch(void* const* d_in, const int* in_sizes, int n_in,
                              void* d_out, int out_size, void* d_ws, size_t ws_size,
                              hipStream_t stream) {
  const float* x = (const float*)d_in[0];
  const float* y = (const float*)d_in[1];
  float* out = (float*)d_out;
  float* ws = (float*)d_ws;
  void* args[] = { (void*)&x, (void*)&y, (void*)&out, (void*)&ws };
  // Cooperative launch only for the co-residency guarantee (we never call
  // cg::grid.sync — all sync is per-batch barriers + publish/poll).
  hipLaunchCooperativeKernel((const void*)sinkhorn_kernel,
                             dim3(NBLOCKS), dim3(NTHREADS), args, 0, stream);
}

// Round 3
// 124.447 us; speedup vs baseline: 4.4850x; 4.4850x over previous
//
#include <hip/hip_runtime.h>

typedef unsigned int uint_t;

constexpr int B = 8;
constexpr int N = 1024;
constexpr int NBLOCKS = 256;
constexpr int NTHREADS = 512;
constexpr int NWAVES = NTHREADS / 64;      // 8
constexpr int BPB = NBLOCKS / B;           // 32 blocks per batch
constexpr int SEG = N / BPB;               // 32 rows per block
constexpr int RPW = SEG / NWAVES;          // 4 rows per wave
constexpr int KPL = N / 64;                // 16 columns per lane
constexpr int MAX_ITER = 100;
constexpr float THRESH = 0.1f;
constexpr float K2 = 14.42695040888963f;         // log2(e)/EPS
constexpr float A2K = 2.0f * K2;
constexpr float NEPSLN2 = -0.06931471805599453f; // -EPS*ln2
constexpr float EPSLOGMU = -0.693146156565634f;  // EPS*log(1/N+1e-8)
constexpr uint_t MAGIC = 0xC0FFEE01u;

// ws word offsets
constexpr int OFF_U      = 0;                    // [B][N]
constexpr int OFF_V      = OFF_U + B * N;        // [B][N]
constexpr int OFF_ERRBLK = OFF_V + B * N;        // [B][32]   written-before-read
constexpr int OFF_ERRBAT = OFF_ERRBLK + 256;     // [100][8]  written-before-read
constexpr int OFF_EMDBLK = OFF_ERRBAT + 800;     // [B][32]   written-before-read
constexpr int OFF_EMDBAT = OFF_EMDBLK + 256;     // [8]       written-before-read
constexpr int OFF_ZERO   = OFF_EMDBAT + 8;       // ---- zeroed region start ----
constexpr int OFF_ERRPUB = OFF_ZERO;             // [100] uint
constexpr int OFF_EMDPUB = OFF_ERRPUB + 100;     // [1] uint
constexpr int OFF_BARCNT = ((OFF_EMDPUB + 1 + 31) / 32) * 32;  // [8][32] stride-32
constexpr int OFF_ZEROEND= OFF_BARCNT + 8 * 32;
constexpr int OFF_INIT   = OFF_ZEROEND;          // [1] uint (MAGIC, not zeroed)

// ---- coherent (sc1) access helpers: bypass non-coherent L1/L2, no fences ----
__device__ __forceinline__ float gload(const float* p) {
  return __hip_atomic_load(p, __ATOMIC_RELAXED, __HIP_MEMORY_SCOPE_AGENT);
}
__device__ __forceinline__ void gstore(float* p, float v) {
  __hip_atomic_store(p, v, __ATOMIC_RELAXED, __HIP_MEMORY_SCOPE_AGENT);
}

__device__ __forceinline__ float wsum(float v) {
#pragma unroll
  for (int o = 32; o; o >>= 1) v += __shfl_xor(v, o);
  return v;
}
__device__ __forceinline__ float wmax(float v) {
#pragma unroll
  for (int o = 32; o; o >>= 1) v = fmaxf(v, __shfl_xor(v, o));
  return v;
}

// Deterministic block-wide sum; every thread returns the same value.
__device__ __forceinline__ float block_sum(float v, float* sh) {
  v = wsum(v);
  const int wave = threadIdx.x >> 6;
  const int lane = threadIdx.x & 63;
  if (lane == 0) sh[wave] = v;
  __syncthreads();
  float tot = 0.f;
#pragma unroll
  for (int w = 0; w < NWAVES; ++w) tot += sh[w];
  __syncthreads();
  return tot;
}

// Per-batch barrier: RELEASE arrival (orders prior sc1 stores), RELAXED spin
// (coherent load, NO cache-invalidate side effects — this was R2's regression).
__device__ __forceinline__ void batch_barrier(uint_t* cnt, uint_t target) {
  __syncthreads();
  if (threadIdx.x == 0) {
    __hip_atomic_fetch_add(cnt, 1u, __ATOMIC_RELEASE, __HIP_MEMORY_SCOPE_AGENT);
    while (__hip_atomic_load(cnt, __ATOMIC_RELAXED, __HIP_MEMORY_SCOPE_AGENT) < target)
      __builtin_amdgcn_s_sleep(1);
  }
  __syncthreads();
}

// One Sinkhorn half-update in base-2 scale (K2 = log2(e)/EPS folded in).
template <bool TRACK>
__device__ __forceinline__ float half_update(
    const float4* s_row, const float4* s_col,
    const float* __restrict__ pin, float* __restrict__ pout,
    int seg, int wave, int lane, bool pin_zero, bool first_out) {
  float p2[KPL];
#pragma unroll
  for (int k = 0; k < KPL; ++k)
    p2[k] = pin_zero ? 0.f : gload(&pin[lane + (k << 6)]) * K2;

  float err = 0.f;
  float a0[RPW], a1[RPW], a2[RPW], X[RPW], m[RPW];
  float vals[RPW][KPL];
#pragma unroll
  for (int rr = 0; rr < RPW; ++rr) {
    float4 r4 = s_row[seg * SEG + wave * RPW + rr];  // wave-uniform: broadcast
    a0[rr] = A2K * r4.x; a1[rr] = A2K * r4.y; a2[rr] = A2K * r4.z;
    X[rr] = -r4.w;        // = K2*|row|^2
    m[rr] = -3.4e38f;
  }
#pragma unroll
  for (int k = 0; k < KPL; ++k) {
    float4 c4 = s_col[lane + (k << 6)];  // ds_read_b128, dense
    float pv = p2[k];
#pragma unroll
    for (int rr = 0; rr < RPW; ++rr) {
      float t = fmaf(a0[rr], c4.x, fmaf(a1[rr], c4.y, fmaf(a2[rr], c4.z, c4.w)));
      float val = fminf(t - X[rr], 0.f) + pv;   // = pv - K2*C
      vals[rr][k] = val;
      m[rr] = fmaxf(m[rr], val);
    }
  }
#pragma unroll
  for (int rr = 0; rr < RPW; ++rr) {
    float mr = wmax(m[rr]);
    float s = 0.f;
#pragma unroll
    for (int k = 0; k < KPL; ++k)
      s += __builtin_amdgcn_exp2f(vals[rr][k] - mr);
    s = wsum(s);
    float lse2 = mr + __builtin_amdgcn_logf(s);       // log2(sum 2^val)
    float pnew = fmaf(NEPSLN2, lse2, EPSLOGMU);
    if (lane == 0) {
      int i = seg * SEG + wave * RPW + rr;
      if (TRACK) {
        float old = first_out ? 0.f : gload(&pout[i]);
        err += fabsf(pnew - old);
      }
      gstore(&pout[i], pnew);
    }
  }
  return err;
}

__global__ void __launch_bounds__(NTHREADS, 1) sinkhorn_kernel(
    const float* __restrict__ xg, const float* __restrict__ yg,
    float* __restrict__ out, float* __restrict__ ws) {
  __shared__ float4 s_x4[N];   // (x0,x1,x2, -K2*|x|^2)
  __shared__ float4 s_y4[N];
  __shared__ float sh_red[NWAVES];

  const int bid = blockIdx.x;
  const int tid = threadIdx.x;
  const int b = bid & 7;       // likely XCD-local per batch; correctness never depends on it
  const int seg = bid >> 3;
  const int wave = tid >> 6;
  const int lane = tid & 63;

  float* u = ws + OFF_U + b * N;
  float* v = ws + OFF_V + b * N;
  float* err_blk = ws + OFF_ERRBLK + b * 32;
  float* err_bat = ws + OFF_ERRBAT;
  float* emd_blk = ws + OFF_EMDBLK + b * 32;
  float* emd_bat = ws + OFF_EMDBAT;
  uint_t* err_pub = (uint_t*)(ws + OFF_ERRPUB);
  uint_t* emd_pub = (uint_t*)(ws + OFF_EMDPUB);
  uint_t* init_flag = (uint_t*)(ws + OFF_INIT);
  uint_t* bar_cnt = (uint_t*)(ws + OFF_BARCNT) + b * 32;

  // Stage points into LDS (overlaps the init handshake below).
  for (int p = tid; p < N; p += NTHREADS) {
    const float* xp = xg + (size_t)(b * N + p) * 3;
    float x0 = xp[0], x1 = xp[1], x2 = xp[2];
    s_x4[p] = make_float4(x0, x1, x2, -K2 * (x0 * x0 + x1 * x1 + x2 * x2));
    const float* yp = yg + (size_t)(b * N + p) * 3;
    float y0 = yp[0], y1 = yp[1], y2 = yp[2];
    s_y4[p] = make_float4(y0, y1, y2, -K2 * (y0 * y0 + y1 * y1 + y2 * y2));
  }

  // Init handshake: block 0 zeroes counters (ws poisoned 0xAA), broadcasts MAGIC.
  // u/v need no init: iteration 0 uses pin_zero/first_out (u=v=0 algebraically).
  if (bid == 0) {
    uint_t* zb = (uint_t*)(ws + OFF_ZERO);
    for (int i = tid; i < OFF_ZEROEND - OFF_ZERO; i += NTHREADS)
      __hip_atomic_store(&zb[i], 0u, __ATOMIC_RELAXED, __HIP_MEMORY_SCOPE_AGENT);
    __syncthreads();
    if (tid == 0)
      __hip_atomic_store(init_flag, MAGIC, __ATOMIC_RELEASE, __HIP_MEMORY_SCOPE_AGENT);
  } else if (tid == 0) {
    while (__hip_atomic_load(init_flag, __ATOMIC_RELAXED, __HIP_MEMORY_SCOPE_AGENT) != MAGIC)
      __builtin_amdgcn_s_sleep(2);
  }
  __syncthreads();

  uint_t bar_target = 0;
  for (int it = 0; it < MAX_ITER; ++it) {
    // ---- u-update (+ err tracking on own rows) ----
    float my_err = half_update<true>(s_x4, s_y4, v, u, seg, wave, lane,
                                     /*pin_zero=*/it == 0, /*first_out=*/it == 0);
    float blk_err = block_sum(my_err, sh_red);
    if (tid == 0) gstore(&err_blk[seg], blk_err);
    bar_target += BPB;
    batch_barrier(bar_cnt, bar_target);   // u + err_blk visible within batch

    // Publish this batch's err early: propagation overlaps v-update compute.
    if (seg == 0 && tid == 0) {
      float s = 0.f;
      for (int q = 0; q < BPB; ++q) s += gload(&err_blk[q]);
      gstore(&err_bat[it * B + b], s);
      __hip_atomic_fetch_add(&err_pub[it], 1u, __ATOMIC_RELEASE, __HIP_MEMORY_SCOPE_AGENT);
    }

    // ---- v-update (uses new u) ----
    half_update<false>(s_y4, s_x4, u, v, seg, wave, lane, false, false);
    bar_target += BPB;
    batch_barrier(bar_cnt, bar_target);   // v visible within batch

    // ---- global convergence decision (uniform across all blocks) ----
    if (tid == 0)
      while (__hip_atomic_load(&err_pub[it], __ATOMIC_RELAXED, __HIP_MEMORY_SCOPE_AGENT) < (uint_t)B)
        __builtin_amdgcn_s_sleep(2);
    __syncthreads();
    float tot = 0.f;
#pragma unroll
    for (int q = 0; q < B; ++q) tot += gload(&err_bat[it * B + q]);
    if (tot * (1.f / (B * N)) < THRESH) break;
  }

  // ---- epilogue: emd_b = sum_ij exp((u_i+v_j-C)/EPS)*C  (in K2 scale) ----
  float p2[KPL];
#pragma unroll
  for (int k = 0; k < KPL; ++k) p2[k] = gload(&v[lane + (k << 6)]) * K2;
  float acc = 0.f;
#pragma unroll
  for (int rr = 0; rr < RPW; ++rr) {
    int i = seg * SEG + wave * RPW + rr;
    float4 r4 = s_x4[i];
    float a0 = A2K * r4.x, a1 = A2K * r4.y, a2 = A2K * r4.z;
    float X = -r4.w;
    float u2 = gload(&u[i]) * K2;
#pragma unroll
    for (int k = 0; k < KPL; ++k) {
      float4 c4 = s_y4[lane + (k << 6)];
      float t = fmaf(a0, c4.x, fmaf(a1, c4.y, fmaf(a2, c4.z, c4.w)));
      float kc = fmaxf(X - t, 0.f);   // K2*C
      acc = fmaf(__builtin_amdgcn_exp2f(u2 + p2[k] - kc), kc, acc);
    }
  }
  float blk = block_sum(acc, sh_red);
  if (tid == 0) gstore(&emd_blk[seg], blk);
  bar_target += BPB;
  batch_barrier(bar_cnt, bar_target);
  if (seg == 0 && tid == 0) {
    float s = 0.f;
    for (int q = 0; q < BPB; ++q) s += gload(&emd_blk[q]);
    gstore(&emd_bat[b], s);
    __hip_atomic_fetch_add(emd_pub, 1u, __ATOMIC_RELEASE, __HIP_MEMORY_SCOPE_AGENT);
  }
  if (bid == 0 && tid == 0) {
    while (__hip_atomic_load(emd_pub, __ATOMIC_RELAXED, __HIP_MEMORY_SCOPE_AGENT) < (uint_t)B)
      __builtin_amdgcn_s_sleep(2);
    float s = 0.f;
#pragma unroll
    for (int q = 0; q < B; ++q) s += gload(&emd_bat[q]);
    out[0] = s * (1.f / (B * K2));
  }
}

extern "C" void kernel_launch(void* const* d_in, const int* in_sizes, int n_in,
                              void* d_out, int out_size, void* d_ws, size_t ws_size,
                              hipStream_t stream) {
  const float* x = (const float*)d_in[0];
  const float* y = (const float*)d_in[1];
  float* out = (float*)d_out;
  float* ws = (float*)d_ws;
  void* args[] = { (void*)&x, (void*)&y, (void*)&out, (void*)&ws };
  // Cooperative launch only for the co-residency guarantee (no cg::grid.sync;
  // all sync is per-batch counters + publish/poll over sc1-coherent atomics).
  hipLaunchCooperativeKernel((const void*)sinkhorn_kernel,
                             dim3(NBLOCKS), dim3(NTHREADS), args, 0, stream);
}